// Round 1
// baseline (1096.389 us; speedup 1.0000x reference)
//
#include <hip/hip_runtime.h>

#define D 96

// -------- GEMM: support[n][j] = sum_k x[n][k] * W[k][j] --------
// Block: 256 threads, 64 rows per block.
// LDS: full W (96x96, 36KB) + X tile (64x96 padded to stride 97, ~24.3KB) = ~61.7KB -> 2 blocks/CU.
// Thread micro-tile: 2 rows x 12 cols. W reads are 3x float4 per k; with 8 col-groups the
// b128 reads cover all 32 banks conflict-free. X reads use stride-97 padding so the 8 distinct
// row addresses per wave land in distinct banks.
__global__ __launch_bounds__(256) void gemm_xw(const float* __restrict__ x,
                                               const float* __restrict__ w,
                                               float* __restrict__ support,
                                               int n) {
    __shared__ float Wl[96 * 96];
    __shared__ float Xl[64 * 97];
    const int tid = threadIdx.x;

    // Stage W: 9216 floats = 2304 float4, 9 per thread.
    {
        const float4* w4 = (const float4*)w;
        float4* W4 = (float4*)Wl;
        #pragma unroll
        for (int i = 0; i < 9; i++) W4[tid + 256 * i] = w4[tid + 256 * i];
    }

    const int row0 = blockIdx.x * 64;
    int nrows = n - row0;
    if (nrows > 64) nrows = 64;

    // Stage X tile into padded LDS (stride 97 floats).
    {
        const float4* x4 = (const float4*)(x + (size_t)row0 * D);
        for (int i = tid; i < nrows * 24; i += 256) {
            int r = i / 24, c = i % 24;
            float4 v = x4[(size_t)r * 24 + c];
            float* dst = &Xl[r * 97 + c * 4];
            dst[0] = v.x; dst[1] = v.y; dst[2] = v.z; dst[3] = v.w;
        }
    }
    __syncthreads();

    const int r0 = (tid >> 3) * 2;      // 0..62 (pair of rows)
    const int c0 = (tid & 7) * 12;      // 0,12,...,84

    float acc0[12], acc1[12];
    #pragma unroll
    for (int j = 0; j < 12; j++) { acc0[j] = 0.f; acc1[j] = 0.f; }

    const float* xr0 = &Xl[r0 * 97];
    const float* xr1 = &Xl[(r0 + 1) * 97];

    #pragma unroll 4
    for (int k = 0; k < 96; k++) {
        float xv0 = xr0[k];
        float xv1 = xr1[k];
        const float* wr = &Wl[k * 96 + c0];
        float4 wa = *(const float4*)(wr);
        float4 wb = *(const float4*)(wr + 4);
        float4 wc = *(const float4*)(wr + 8);
        acc0[0] += xv0 * wa.x;  acc1[0] += xv1 * wa.x;
        acc0[1] += xv0 * wa.y;  acc1[1] += xv1 * wa.y;
        acc0[2] += xv0 * wa.z;  acc1[2] += xv1 * wa.z;
        acc0[3] += xv0 * wa.w;  acc1[3] += xv1 * wa.w;
        acc0[4] += xv0 * wb.x;  acc1[4] += xv1 * wb.x;
        acc0[5] += xv0 * wb.y;  acc1[5] += xv1 * wb.y;
        acc0[6] += xv0 * wb.z;  acc1[6] += xv1 * wb.z;
        acc0[7] += xv0 * wb.w;  acc1[7] += xv1 * wb.w;
        acc0[8] += xv0 * wc.x;  acc1[8] += xv1 * wc.x;
        acc0[9] += xv0 * wc.y;  acc1[9] += xv1 * wc.y;
        acc0[10] += xv0 * wc.z; acc1[10] += xv1 * wc.z;
        acc0[11] += xv0 * wc.w; acc1[11] += xv1 * wc.w;
    }

    // Store (col offsets 0/12/..: byte offset 48*cg, 16B-aligned).
    if (row0 + r0 < n) {
        float* o = support + (size_t)(row0 + r0) * D + c0;
        ((float4*)o)[0] = make_float4(acc0[0], acc0[1], acc0[2], acc0[3]);
        ((float4*)o)[1] = make_float4(acc0[4], acc0[5], acc0[6], acc0[7]);
        ((float4*)o)[2] = make_float4(acc0[8], acc0[9], acc0[10], acc0[11]);
    }
    if (row0 + r0 + 1 < n) {
        float* o = support + (size_t)(row0 + r0 + 1) * D + c0;
        ((float4*)o)[0] = make_float4(acc1[0], acc1[1], acc1[2], acc1[3]);
        ((float4*)o)[1] = make_float4(acc1[4], acc1[5], acc1[6], acc1[7]);
        ((float4*)o)[2] = make_float4(acc1[8], acc1[9], acc1[10], acc1[11]);
    }
}

// -------- out init: out[n][j] = b[j] --------
__global__ void init_out(float* __restrict__ out, const float* __restrict__ b, int total4) {
    int idx = blockIdx.x * blockDim.x + threadIdx.x;
    if (idx >= total4) return;
    int c = idx - (idx / 24) * 24;  // idx % 24
    ((float4*)out)[idx] = ((const float4*)b)[c];
}

// -------- scatter: out[row[e]] += val[e] * support[col[e]] --------
// 24 threads per edge (one float4 chunk of 96 feats each), 8 edges per 192-thread block.
__global__ __launch_bounds__(192) void scatter_edges(const int* __restrict__ erow,
                                                     const int* __restrict__ ecol,
                                                     const float* __restrict__ eval_,
                                                     const float* __restrict__ support,
                                                     float* __restrict__ out,
                                                     int E) {
    const int tid = threadIdx.x;
    const int el = tid / 24;            // 0..7
    const int c = tid - el * 24;        // chunk 0..23
    const int e = blockIdx.x * 8 + el;
    if (e >= E) return;

    const int r = erow[e];
    const int cl = ecol[e];
    const float v = eval_[e];

    float4 s = ((const float4*)support)[(size_t)cl * 24 + c];
    float* o = out + (size_t)r * D + c * 4;
    atomicAdd(o + 0, v * s.x);
    atomicAdd(o + 1, v * s.y);
    atomicAdd(o + 2, v * s.z);
    atomicAdd(o + 3, v * s.w);
}

extern "C" void kernel_launch(void* const* d_in, const int* in_sizes, int n_in,
                              void* d_out, int out_size, void* d_ws, size_t ws_size,
                              hipStream_t stream) {
    const float* x     = (const float*)d_in[0];
    const int*   erow  = (const int*)d_in[1];
    const int*   ecol  = (const int*)d_in[2];
    const float* eval_ = (const float*)d_in[3];
    const float* w     = (const float*)d_in[4];
    const float* b     = (const float*)d_in[5];
    float* out = (float*)d_out;
    float* support = (float*)d_ws;   // 50000*96*4 = 19.2 MB scratch

    const int n = in_sizes[0] / D;   // 50000
    const int E = in_sizes[1];       // 800000

    gemm_xw<<<(n + 63) / 64, 256, 0, stream>>>(x, w, support, n);
    init_out<<<(n * 24 + 255) / 256, 256, 0, stream>>>(out, b, n * 24);
    scatter_edges<<<(E + 7) / 8, 192, 0, stream>>>(erow, ecol, eval_, support, out, E);
}

// Round 2
// 343.234 us; speedup vs baseline: 3.1943x; 3.1943x over previous
//
#include <hip/hip_runtime.h>

#define D 96
#define NROWS_MAX 50000

// -------- GEMM: support[n][j] = sum_k x[n][k] * W[k][j] --------
__global__ __launch_bounds__(256) void gemm_xw(const float* __restrict__ x,
                                               const float* __restrict__ w,
                                               float* __restrict__ support,
                                               int n) {
    __shared__ float Wl[96 * 96];
    __shared__ float Xl[64 * 97];
    const int tid = threadIdx.x;

    {
        const float4* w4 = (const float4*)w;
        float4* W4 = (float4*)Wl;
        #pragma unroll
        for (int i = 0; i < 9; i++) W4[tid + 256 * i] = w4[tid + 256 * i];
    }

    const int row0 = blockIdx.x * 64;
    int nrows = n - row0;
    if (nrows > 64) nrows = 64;

    {
        const float4* x4 = (const float4*)(x + (size_t)row0 * D);
        for (int i = tid; i < nrows * 24; i += 256) {
            int r = i / 24, c = i % 24;
            float4 v = x4[(size_t)r * 24 + c];
            float* dst = &Xl[r * 97 + c * 4];
            dst[0] = v.x; dst[1] = v.y; dst[2] = v.z; dst[3] = v.w;
        }
    }
    __syncthreads();

    const int r0 = (tid >> 3) * 2;
    const int c0 = (tid & 7) * 12;

    float acc0[12], acc1[12];
    #pragma unroll
    for (int j = 0; j < 12; j++) { acc0[j] = 0.f; acc1[j] = 0.f; }

    const float* xr0 = &Xl[r0 * 97];
    const float* xr1 = &Xl[(r0 + 1) * 97];

    #pragma unroll 4
    for (int k = 0; k < 96; k++) {
        float xv0 = xr0[k];
        float xv1 = xr1[k];
        const float* wr = &Wl[k * 96 + c0];
        float4 wa = *(const float4*)(wr);
        float4 wb = *(const float4*)(wr + 4);
        float4 wc = *(const float4*)(wr + 8);
        acc0[0] += xv0 * wa.x;  acc1[0] += xv1 * wa.x;
        acc0[1] += xv0 * wa.y;  acc1[1] += xv1 * wa.y;
        acc0[2] += xv0 * wa.z;  acc1[2] += xv1 * wa.z;
        acc0[3] += xv0 * wa.w;  acc1[3] += xv1 * wa.w;
        acc0[4] += xv0 * wb.x;  acc1[4] += xv1 * wb.x;
        acc0[5] += xv0 * wb.y;  acc1[5] += xv1 * wb.y;
        acc0[6] += xv0 * wb.z;  acc1[6] += xv1 * wb.z;
        acc0[7] += xv0 * wb.w;  acc1[7] += xv1 * wb.w;
        acc0[8] += xv0 * wc.x;  acc1[8] += xv1 * wc.x;
        acc0[9] += xv0 * wc.y;  acc1[9] += xv1 * wc.y;
        acc0[10] += xv0 * wc.z; acc1[10] += xv1 * wc.z;
        acc0[11] += xv0 * wc.w; acc1[11] += xv1 * wc.w;
    }

    if (row0 + r0 < n) {
        float* o = support + (size_t)(row0 + r0) * D + c0;
        ((float4*)o)[0] = make_float4(acc0[0], acc0[1], acc0[2], acc0[3]);
        ((float4*)o)[1] = make_float4(acc0[4], acc0[5], acc0[6], acc0[7]);
        ((float4*)o)[2] = make_float4(acc0[8], acc0[9], acc0[10], acc0[11]);
    }
    if (row0 + r0 + 1 < n) {
        float* o = support + (size_t)(row0 + r0 + 1) * D + c0;
        ((float4*)o)[0] = make_float4(acc1[0], acc1[1], acc1[2], acc1[3]);
        ((float4*)o)[1] = make_float4(acc1[4], acc1[5], acc1[6], acc1[7]);
        ((float4*)o)[2] = make_float4(acc1[8], acc1[9], acc1[10], acc1[11]);
    }
}

// -------- CSR build step 1: histogram of edge rows --------
__global__ void hist_rows(const int* __restrict__ erow, int* __restrict__ cnt, int E) {
    int e = blockIdx.x * blockDim.x + threadIdx.x;
    if (e < E) atomicAdd(&cnt[erow[e]], 1);
}

// -------- CSR build step 2: exclusive scan over cnt[0..N) -> row_start[0..N], cursor copy --------
// Single block of 1024 threads, 49 items each covers N+1 = 50001.
__global__ __launch_bounds__(1024) void scan_counts(const int* __restrict__ cnt,
                                                    int* __restrict__ row_start,
                                                    int* __restrict__ cursor,
                                                    int N) {
    __shared__ int part[1024];
    const int t = threadIdx.x;
    const int ITEMS = 49;
    const int base = t * ITEMS;

    int total = 0;
    #pragma unroll 1
    for (int i = base; i < base + ITEMS && i < N; i++) total += cnt[i];
    part[t] = total;
    __syncthreads();

    // Hillis-Steele inclusive scan over 1024 partials
    int val = total;
    #pragma unroll
    for (int ofs = 1; ofs < 1024; ofs <<= 1) {
        int other = (t >= ofs) ? part[t - ofs] : 0;
        __syncthreads();
        val += other;
        part[t] = val;
        __syncthreads();
    }
    int running = val - total;  // exclusive prefix of this thread's chunk

    #pragma unroll 1
    for (int i = base; i < base + ITEMS && i <= N; i++) {
        row_start[i] = running;
        if (i < N) cursor[i] = running;
        running += (i < N) ? cnt[i] : 0;
    }
}

// -------- CSR build step 3: permute (col,val) into row-sorted order --------
__global__ void bucket_edges(const int* __restrict__ erow, const int* __restrict__ ecol,
                             const float* __restrict__ eval_, int* __restrict__ cursor,
                             int* __restrict__ pcol, float* __restrict__ pval, int E) {
    int e = blockIdx.x * blockDim.x + threadIdx.x;
    if (e >= E) return;
    int slot = atomicAdd(&cursor[erow[e]], 1);
    pcol[slot] = ecol[e];
    pval[slot] = eval_[e];
}

// -------- segment-sum: out[r] = b + sum_{e in row r} pval[e] * support[pcol[e]] --------
// 24 threads per row (one float4 chunk each), 8 rows per 192-thread block. No atomics.
__global__ __launch_bounds__(192) void accumulate_rows(const int* __restrict__ row_start,
                                                       const int* __restrict__ pcol,
                                                       const float* __restrict__ pval,
                                                       const float* __restrict__ support,
                                                       const float* __restrict__ b,
                                                       float* __restrict__ out,
                                                       int N) {
    const int tid = threadIdx.x;
    const int rl = tid / 24;
    const int c = tid - rl * 24;
    const int r = blockIdx.x * 8 + rl;
    if (r >= N) return;

    const int s = row_start[r];
    const int eend = row_start[r + 1];

    float4 acc = ((const float4*)b)[c];
    const float4* sup4 = (const float4*)support;

    int e = s;
    // 2-wide unroll for memory-level parallelism on the random gathers
    for (; e + 1 < eend; e += 2) {
        int c0 = pcol[e], c1 = pcol[e + 1];
        float v0 = pval[e], v1 = pval[e + 1];
        float4 s0 = sup4[(size_t)c0 * 24 + c];
        float4 s1 = sup4[(size_t)c1 * 24 + c];
        acc.x += v0 * s0.x + v1 * s1.x;
        acc.y += v0 * s0.y + v1 * s1.y;
        acc.z += v0 * s0.z + v1 * s1.z;
        acc.w += v0 * s0.w + v1 * s1.w;
    }
    if (e < eend) {
        int c0 = pcol[e];
        float v0 = pval[e];
        float4 s0 = sup4[(size_t)c0 * 24 + c];
        acc.x += v0 * s0.x;
        acc.y += v0 * s0.y;
        acc.z += v0 * s0.z;
        acc.w += v0 * s0.w;
    }
    ((float4*)out)[(size_t)r * 24 + c] = acc;
}

extern "C" void kernel_launch(void* const* d_in, const int* in_sizes, int n_in,
                              void* d_out, int out_size, void* d_ws, size_t ws_size,
                              hipStream_t stream) {
    const float* x     = (const float*)d_in[0];
    const int*   erow  = (const int*)d_in[1];
    const int*   ecol  = (const int*)d_in[2];
    const float* eval_ = (const float*)d_in[3];
    const float* w     = (const float*)d_in[4];
    const float* b     = (const float*)d_in[5];
    float* out = (float*)d_out;

    const int n = in_sizes[0] / D;   // 50000
    const int E = in_sizes[1];       // 800000

    // Workspace layout (4B units):
    // [0, n*24)                    support    (19.2 MB)
    // then cnt (n), row_start (n+1), cursor (n), pcol (E), pval (E)  (~26 MB total)
    float* support  = (float*)d_ws;
    int*   cnt      = (int*)(support + (size_t)n * 24 * 4 / 4 * 1);  // support + n*96
    // (support has n*96 floats)
    cnt = (int*)((float*)d_ws + (size_t)n * 96);
    int*   row_start = cnt + n;
    int*   cursor    = row_start + (n + 1);
    int*   pcol      = cursor + n;
    float* pval      = (float*)(pcol + E);

    hipMemsetAsync(cnt, 0, (size_t)n * sizeof(int), stream);

    gemm_xw<<<(n + 63) / 64, 256, 0, stream>>>(x, w, support, n);
    hist_rows<<<(E + 255) / 256, 256, 0, stream>>>(erow, cnt, E);
    scan_counts<<<1, 1024, 0, stream>>>(cnt, row_start, cursor, n);
    bucket_edges<<<(E + 255) / 256, 256, 0, stream>>>(erow, ecol, eval_, cursor, pcol, pval, E);
    accumulate_rows<<<(n + 7) / 8, 192, 0, stream>>>(row_start, pcol, pval, support, b, out, n);
}

// Round 3
// 215.674 us; speedup vs baseline: 5.0835x; 1.5914x over previous
//
#include <hip/hip_runtime.h>

#define D 96

// -------- GEMM: support[n][j] = sum_k x[n][k] * W[k][j] --------
__global__ __launch_bounds__(256) void gemm_xw(const float* __restrict__ x,
                                               const float* __restrict__ w,
                                               float* __restrict__ support,
                                               int n) {
    __shared__ float Wl[96 * 96];
    __shared__ float Xl[64 * 97];
    const int tid = threadIdx.x;

    {
        const float4* w4 = (const float4*)w;
        float4* W4 = (float4*)Wl;
        #pragma unroll
        for (int i = 0; i < 9; i++) W4[tid + 256 * i] = w4[tid + 256 * i];
    }

    const int row0 = blockIdx.x * 64;
    int nrows = n - row0;
    if (nrows > 64) nrows = 64;

    {
        const float4* x4 = (const float4*)(x + (size_t)row0 * D);
        for (int i = tid; i < nrows * 24; i += 256) {
            int r = i / 24, c = i % 24;
            float4 v = x4[(size_t)r * 24 + c];
            float* dst = &Xl[r * 97 + c * 4];
            dst[0] = v.x; dst[1] = v.y; dst[2] = v.z; dst[3] = v.w;
        }
    }
    __syncthreads();

    const int r0 = (tid >> 3) * 2;
    const int c0 = (tid & 7) * 12;

    float acc0[12], acc1[12];
    #pragma unroll
    for (int j = 0; j < 12; j++) { acc0[j] = 0.f; acc1[j] = 0.f; }

    const float* xr0 = &Xl[r0 * 97];
    const float* xr1 = &Xl[(r0 + 1) * 97];

    #pragma unroll 4
    for (int k = 0; k < 96; k++) {
        float xv0 = xr0[k];
        float xv1 = xr1[k];
        const float* wr = &Wl[k * 96 + c0];
        float4 wa = *(const float4*)(wr);
        float4 wb = *(const float4*)(wr + 4);
        float4 wc = *(const float4*)(wr + 8);
        acc0[0] += xv0 * wa.x;  acc1[0] += xv1 * wa.x;
        acc0[1] += xv0 * wa.y;  acc1[1] += xv1 * wa.y;
        acc0[2] += xv0 * wa.z;  acc1[2] += xv1 * wa.z;
        acc0[3] += xv0 * wa.w;  acc1[3] += xv1 * wa.w;
        acc0[4] += xv0 * wb.x;  acc1[4] += xv1 * wb.x;
        acc0[5] += xv0 * wb.y;  acc1[5] += xv1 * wb.y;
        acc0[6] += xv0 * wb.z;  acc1[6] += xv1 * wb.z;
        acc0[7] += xv0 * wb.w;  acc1[7] += xv1 * wb.w;
        acc0[8] += xv0 * wc.x;  acc1[8] += xv1 * wc.x;
        acc0[9] += xv0 * wc.y;  acc1[9] += xv1 * wc.y;
        acc0[10] += xv0 * wc.z; acc1[10] += xv1 * wc.z;
        acc0[11] += xv0 * wc.w; acc1[11] += xv1 * wc.w;
    }

    if (row0 + r0 < n) {
        float* o = support + (size_t)(row0 + r0) * D + c0;
        ((float4*)o)[0] = make_float4(acc0[0], acc0[1], acc0[2], acc0[3]);
        ((float4*)o)[1] = make_float4(acc0[4], acc0[5], acc0[6], acc0[7]);
        ((float4*)o)[2] = make_float4(acc0[8], acc0[9], acc0[10], acc0[11]);
    }
    if (row0 + r0 + 1 < n) {
        float* o = support + (size_t)(row0 + r0 + 1) * D + c0;
        ((float4*)o)[0] = make_float4(acc1[0], acc1[1], acc1[2], acc1[3]);
        ((float4*)o)[1] = make_float4(acc1[4], acc1[5], acc1[6], acc1[7]);
        ((float4*)o)[2] = make_float4(acc1[8], acc1[9], acc1[10], acc1[11]);
    }
}

// -------- build per-row linked lists: next[e] = old head of row[e] --------
__global__ void build_lists(const int* __restrict__ erow, int* __restrict__ head,
                            int* __restrict__ next, int E) {
    int e = blockIdx.x * blockDim.x + threadIdx.x;
    if (e >= E) return;
    int r = erow[e];
    int old = atomicExch(&head[r], e);
    next[e] = old;
}

// -------- segment-sum via list traversal: out[r] = b + sum pval*support[pcol] --------
// 24 threads per row (one float4 chunk each), 8 rows per 192-thread block.
// next/ecol/eval loads are wave-broadcast (uniform across the 24 lanes of a row group).
__global__ __launch_bounds__(192) void accumulate_ll(const int* __restrict__ head,
                                                     const int* __restrict__ next,
                                                     const int* __restrict__ ecol,
                                                     const float* __restrict__ eval_,
                                                     const float* __restrict__ support,
                                                     const float* __restrict__ b,
                                                     float* __restrict__ out,
                                                     int N) {
    const int tid = threadIdx.x;
    const int rl = tid / 24;
    const int c = tid - rl * 24;
    const int r = blockIdx.x * 8 + rl;
    if (r >= N) return;

    float4 acc = ((const float4*)b)[c];
    const float4* sup4 = (const float4*)support;

    int e = head[r];
    while (e >= 0) {
        int col = ecol[e];
        float v = eval_[e];
        int en = next[e];          // issue chase load before the gather
        float4 s = sup4[(size_t)col * 24 + c];
        acc.x += v * s.x;
        acc.y += v * s.y;
        acc.z += v * s.z;
        acc.w += v * s.w;
        e = en;
    }
    ((float4*)out)[(size_t)r * 24 + c] = acc;
}

extern "C" void kernel_launch(void* const* d_in, const int* in_sizes, int n_in,
                              void* d_out, int out_size, void* d_ws, size_t ws_size,
                              hipStream_t stream) {
    const float* x     = (const float*)d_in[0];
    const int*   erow  = (const int*)d_in[1];
    const int*   ecol  = (const int*)d_in[2];
    const float* eval_ = (const float*)d_in[3];
    const float* w     = (const float*)d_in[4];
    const float* b     = (const float*)d_in[5];
    float* out = (float*)d_out;

    const int n = in_sizes[0] / D;   // 50000
    const int E = in_sizes[1];       // 800000

    // Workspace layout (floats/ints, 4B units):
    //   support : n*96 floats (19.2 MB)
    //   head    : n ints      (200 KB)
    //   next    : E ints      (3.2 MB)
    float* support = (float*)d_ws;
    int*   head    = (int*)((float*)d_ws + (size_t)n * 96);
    int*   next    = head + n;

    hipMemsetAsync(head, 0xFF, (size_t)n * sizeof(int), stream);  // head[r] = -1

    gemm_xw<<<(n + 63) / 64, 256, 0, stream>>>(x, w, support, n);
    build_lists<<<(E + 255) / 256, 256, 0, stream>>>(erow, head, next, E);
    accumulate_ll<<<(n + 7) / 8, 192, 0, stream>>>(head, next, ecol, eval_, support, b, out, n);
}

// Round 4
// 191.792 us; speedup vs baseline: 5.7165x; 1.1245x over previous
//
#include <hip/hip_runtime.h>
#include <hip/hip_fp16.h>

#define D 96

// -------- GEMM: support[n][j] = (half) sum_k x[n][k] * W[k][j] --------
// fp32 compute, fp16 output (halves the downstream gather traffic).
__global__ __launch_bounds__(256) void gemm_xw(const float* __restrict__ x,
                                               const float* __restrict__ w,
                                               __half* __restrict__ support,
                                               int n) {
    __shared__ float Wl[96 * 96];
    __shared__ float Xl[64 * 97];
    const int tid = threadIdx.x;

    {
        const float4* w4 = (const float4*)w;
        float4* W4 = (float4*)Wl;
        #pragma unroll
        for (int i = 0; i < 9; i++) W4[tid + 256 * i] = w4[tid + 256 * i];
    }

    const int row0 = blockIdx.x * 64;
    int nrows = n - row0;
    if (nrows > 64) nrows = 64;

    {
        const float4* x4 = (const float4*)(x + (size_t)row0 * D);
        for (int i = tid; i < nrows * 24; i += 256) {
            int r = i / 24, c = i % 24;
            float4 v = x4[(size_t)r * 24 + c];
            float* dst = &Xl[r * 97 + c * 4];
            dst[0] = v.x; dst[1] = v.y; dst[2] = v.z; dst[3] = v.w;
        }
    }
    __syncthreads();

    const int r0 = (tid >> 3) * 2;
    const int c0 = (tid & 7) * 12;

    float acc0[12], acc1[12];
    #pragma unroll
    for (int j = 0; j < 12; j++) { acc0[j] = 0.f; acc1[j] = 0.f; }

    const float* xr0 = &Xl[r0 * 97];
    const float* xr1 = &Xl[(r0 + 1) * 97];

    #pragma unroll 4
    for (int k = 0; k < 96; k++) {
        float xv0 = xr0[k];
        float xv1 = xr1[k];
        const float* wr = &Wl[k * 96 + c0];
        float4 wa = *(const float4*)(wr);
        float4 wb = *(const float4*)(wr + 4);
        float4 wc = *(const float4*)(wr + 8);
        acc0[0] += xv0 * wa.x;  acc1[0] += xv1 * wa.x;
        acc0[1] += xv0 * wa.y;  acc1[1] += xv1 * wa.y;
        acc0[2] += xv0 * wa.z;  acc1[2] += xv1 * wa.z;
        acc0[3] += xv0 * wa.w;  acc1[3] += xv1 * wa.w;
        acc0[4] += xv0 * wb.x;  acc1[4] += xv1 * wb.x;
        acc0[5] += xv0 * wb.y;  acc1[5] += xv1 * wb.y;
        acc0[6] += xv0 * wb.z;  acc1[6] += xv1 * wb.z;
        acc0[7] += xv0 * wb.w;  acc1[7] += xv1 * wb.w;
        acc0[8] += xv0 * wc.x;  acc1[8] += xv1 * wc.x;
        acc0[9] += xv0 * wc.y;  acc1[9] += xv1 * wc.y;
        acc0[10] += xv0 * wc.z; acc1[10] += xv1 * wc.z;
        acc0[11] += xv0 * wc.w; acc1[11] += xv1 * wc.w;
    }

    if (row0 + r0 < n) {
        __half2* o = (__half2*)(support + (size_t)(row0 + r0) * D + c0);
        o[0] = __floats2half2_rn(acc0[0], acc0[1]);
        o[1] = __floats2half2_rn(acc0[2], acc0[3]);
        o[2] = __floats2half2_rn(acc0[4], acc0[5]);
        o[3] = __floats2half2_rn(acc0[6], acc0[7]);
        o[4] = __floats2half2_rn(acc0[8], acc0[9]);
        o[5] = __floats2half2_rn(acc0[10], acc0[11]);
    }
    if (row0 + r0 + 1 < n) {
        __half2* o = (__half2*)(support + (size_t)(row0 + r0 + 1) * D + c0);
        o[0] = __floats2half2_rn(acc1[0], acc1[1]);
        o[1] = __floats2half2_rn(acc1[2], acc1[3]);
        o[2] = __floats2half2_rn(acc1[4], acc1[5]);
        o[3] = __floats2half2_rn(acc1[6], acc1[7]);
        o[4] = __floats2half2_rn(acc1[8], acc1[9]);
        o[5] = __floats2half2_rn(acc1[10], acc1[11]);
    }
}

// -------- build per-row linked lists + packed (col,val) --------
__global__ void build_lists(const int* __restrict__ erow, const int* __restrict__ ecol,
                            const float* __restrict__ eval_,
                            int* __restrict__ head, int* __restrict__ next,
                            int2* __restrict__ cv, int E) {
    int e = blockIdx.x * blockDim.x + threadIdx.x;
    if (e >= E) return;
    next[e] = atomicExch(&head[erow[e]], e);
    cv[e] = make_int2(ecol[e], __float_as_int(eval_[e]));
}

// -------- segment-sum via list traversal, fp16 support gathers --------
// 12 lanes per row, each owns one 16B chunk (8 halves); 16 rows per 192-thread block.
__global__ __launch_bounds__(192) void accumulate_ll(const int* __restrict__ head,
                                                     const int* __restrict__ next,
                                                     const int2* __restrict__ cv,
                                                     const __half* __restrict__ support,
                                                     const float* __restrict__ b,
                                                     float* __restrict__ out,
                                                     int N) {
    const int tid = threadIdx.x;
    const int rl = tid / 12;
    const int c = tid - rl * 12;       // chunk 0..11 (16B each)
    const int r = blockIdx.x * 16 + rl;
    if (r >= N) return;

    float4 accA = ((const float4*)b)[c * 2];
    float4 accB = ((const float4*)b)[c * 2 + 1];

    const float4* sup16 = (const float4*)support;  // 16B chunks; row = 12 chunks

    int e = head[r];
    while (e >= 0) {
        int2 cvv = cv[e];
        int en = next[e];                           // chase load issued early
        float v = __int_as_float(cvv.y);
        float4 raw = sup16[(size_t)cvv.x * 12 + c]; // 8 halves
        const __half2* h = (const __half2*)&raw;
        float2 f0 = __half22float2(h[0]);
        float2 f1 = __half22float2(h[1]);
        float2 f2 = __half22float2(h[2]);
        float2 f3 = __half22float2(h[3]);
        accA.x += v * f0.x;  accA.y += v * f0.y;
        accA.z += v * f1.x;  accA.w += v * f1.y;
        accB.x += v * f2.x;  accB.y += v * f2.y;
        accB.z += v * f3.x;  accB.w += v * f3.y;
        e = en;
    }
    float4* o = (float4*)(out + (size_t)r * D) + c * 2;
    o[0] = accA;
    o[1] = accB;
}

extern "C" void kernel_launch(void* const* d_in, const int* in_sizes, int n_in,
                              void* d_out, int out_size, void* d_ws, size_t ws_size,
                              hipStream_t stream) {
    const float* x     = (const float*)d_in[0];
    const int*   erow  = (const int*)d_in[1];
    const int*   ecol  = (const int*)d_in[2];
    const float* eval_ = (const float*)d_in[3];
    const float* w     = (const float*)d_in[4];
    const float* b     = (const float*)d_in[5];
    float* out = (float*)d_out;

    const int n = in_sizes[0] / D;   // 50000
    const int E = in_sizes[1];       // 800000

    // Workspace layout (bytes):
    //   support : n*96 halves   (9.6 MB)
    //   head    : n ints        (200 KB)
    //   next    : E ints        (3.2 MB)
    //   cv      : E int2        (6.4 MB)   -- 8B aligned (offset 13,000,000)
    __half* support = (__half*)d_ws;
    int*    head    = (int*)((char*)d_ws + (size_t)n * D * sizeof(__half));
    int*    next    = head + n;
    int2*   cv      = (int2*)(next + E);

    hipMemsetAsync(head, 0xFF, (size_t)n * sizeof(int), stream);  // head[r] = -1

    gemm_xw<<<(n + 63) / 64, 256, 0, stream>>>(x, w, support, n);
    build_lists<<<(E + 255) / 256, 256, 0, stream>>>(erow, ecol, eval_, head, next, cv, E);
    accumulate_ll<<<(n + 15) / 16, 192, 0, stream>>>(head, next, cv, support, b, out, n);
}

// Round 5
// 183.799 us; speedup vs baseline: 5.9652x; 1.0435x over previous
//
#include <hip/hip_runtime.h>
#include <hip/hip_fp16.h>

#define D 96

typedef __attribute__((ext_vector_type(8))) short short8;
typedef __attribute__((ext_vector_type(4))) float f32x4;

__device__ inline unsigned short f32_to_bf16_rne(float f) {
    unsigned int u = __float_as_uint(f);
    unsigned int r = u + 0x7FFFu + ((u >> 16) & 1u);
    return (unsigned short)(r >> 16);
}

// -------- prep: build the 18 B-fragments (bf16) of W into global scratch --------
// Fragment f = ct*3+kc; element (f, lane, j) = W[k=kc*32+(lane>>4)*8+j][n=ct*16+(lane&15)].
// Total 18*64*8 = 9216 bf16 = 18 KB. One-time per launch, L2-resident afterwards.
__global__ __launch_bounds__(256) void prep_bfrags(const float* __restrict__ w,
                                                   unsigned short* __restrict__ bfrag) {
    for (int idx = blockIdx.x * 256 + threadIdx.x; idx < 9216; idx += gridDim.x * 256) {
        int j = idx & 7;
        int lane = (idx >> 3) & 63;
        int f = idx >> 9;                 // 0..17
        int ct = f / 3, kc = f - ct * 3;
        int k = kc * 32 + (lane >> 4) * 8 + j;
        int n = ct * 16 + (lane & 15);
        bfrag[idx] = f32_to_bf16_rne(w[k * 96 + n]);
    }
}

// -------- GEMM via MFMA: support[m][n] = (half) sum_k x[m][k] * W[k][n] --------
// 4 waves/block, one 16-row tile per wave. No LDS, no barriers.
// A-frag: A[m=lane&15][k=quad*8+j]; B-frag preloaded; C/D: col=lane&15, row=quad*4+reg.
__global__ __launch_bounds__(256) void gemm_mfma(const float* __restrict__ x,
                                                 const unsigned short* __restrict__ bfrag,
                                                 __half* __restrict__ support,
                                                 int n) {
    const int lane = threadIdx.x & 63;
    const int wave = threadIdx.x >> 6;
    const int m0 = (blockIdx.x * 4 + wave) * 16;
    if (m0 >= n) return;

    // 18 B-frags into registers (coalesced, identical for every wave -> L2 hits)
    short8 bf[18];
    const short8* bsrc = (const short8*)bfrag;
    #pragma unroll
    for (int f = 0; f < 18; f++) bf[f] = bsrc[f * 64 + lane];

    f32x4 acc[6];
    #pragma unroll
    for (int ct = 0; ct < 6; ct++) acc[ct] = (f32x4){0.f, 0.f, 0.f, 0.f};

    const int quad = lane >> 4;
    const int row = m0 + (lane & 15);
    const float4* xrow = (const float4*)(x + (size_t)row * D);

    #pragma unroll
    for (int kc = 0; kc < 3; kc++) {
        float4 f0 = xrow[kc * 8 + quad * 2 + 0];
        float4 f1 = xrow[kc * 8 + quad * 2 + 1];
        short8 a;
        a[0] = (short)f32_to_bf16_rne(f0.x);
        a[1] = (short)f32_to_bf16_rne(f0.y);
        a[2] = (short)f32_to_bf16_rne(f0.z);
        a[3] = (short)f32_to_bf16_rne(f0.w);
        a[4] = (short)f32_to_bf16_rne(f1.x);
        a[5] = (short)f32_to_bf16_rne(f1.y);
        a[6] = (short)f32_to_bf16_rne(f1.z);
        a[7] = (short)f32_to_bf16_rne(f1.w);
        #pragma unroll
        for (int ct = 0; ct < 6; ct++)
            acc[ct] = __builtin_amdgcn_mfma_f32_16x16x32_bf16(a, bf[ct * 3 + kc], acc[ct], 0, 0, 0);
    }

    // Epilogue: D[row=quad*4+j][col=lane&15] per col-tile, emit fp16.
    const int col = lane & 15;
    const int rbase = m0 + quad * 4;
    #pragma unroll
    for (int ct = 0; ct < 6; ct++) {
        #pragma unroll
        for (int j = 0; j < 4; j++) {
            support[(size_t)(rbase + j) * D + ct * 16 + col] = __float2half(acc[ct][j]);
        }
    }
}

// -------- build per-row linked lists + packed (col,val) --------
__global__ void build_lists(const int* __restrict__ erow, const int* __restrict__ ecol,
                            const float* __restrict__ eval_,
                            int* __restrict__ head, int* __restrict__ next,
                            int2* __restrict__ cv, int E) {
    int e = blockIdx.x * blockDim.x + threadIdx.x;
    if (e >= E) return;
    next[e] = atomicExch(&head[erow[e]], e);
    cv[e] = make_int2(ecol[e], __float_as_int(eval_[e]));
}

// -------- segment-sum via list traversal, fp16 support gathers --------
// 12 lanes per row (16B chunk each), 16 rows per 192-thread block.
__global__ __launch_bounds__(192) void accumulate_ll(const int* __restrict__ head,
                                                     const int* __restrict__ next,
                                                     const int2* __restrict__ cv,
                                                     const __half* __restrict__ support,
                                                     const float* __restrict__ b,
                                                     float* __restrict__ out,
                                                     int N) {
    const int tid = threadIdx.x;
    const int rl = tid / 12;
    const int c = tid - rl * 12;
    const int r = blockIdx.x * 16 + rl;
    if (r >= N) return;

    float4 accA = ((const float4*)b)[c * 2];
    float4 accB = ((const float4*)b)[c * 2 + 1];

    const float4* sup16 = (const float4*)support;

    int e = head[r];
    while (e >= 0) {
        int2 cvv = cv[e];
        int en = next[e];
        float v = __int_as_float(cvv.y);
        float4 raw = sup16[(size_t)cvv.x * 12 + c];
        const __half2* h = (const __half2*)&raw;
        float2 f0 = __half22float2(h[0]);
        float2 f1 = __half22float2(h[1]);
        float2 f2 = __half22float2(h[2]);
        float2 f3 = __half22float2(h[3]);
        accA.x += v * f0.x;  accA.y += v * f0.y;
        accA.z += v * f1.x;  accA.w += v * f1.y;
        accB.x += v * f2.x;  accB.y += v * f2.y;
        accB.z += v * f3.x;  accB.w += v * f3.y;
        e = en;
    }
    float4* o = (float4*)(out + (size_t)r * D) + c * 2;
    o[0] = accA;
    o[1] = accB;
}

extern "C" void kernel_launch(void* const* d_in, const int* in_sizes, int n_in,
                              void* d_out, int out_size, void* d_ws, size_t ws_size,
                              hipStream_t stream) {
    const float* x     = (const float*)d_in[0];
    const int*   erow  = (const int*)d_in[1];
    const int*   ecol  = (const int*)d_in[2];
    const float* eval_ = (const float*)d_in[3];
    const float* w     = (const float*)d_in[4];
    const float* b     = (const float*)d_in[5];
    float* out = (float*)d_out;

    const int n = in_sizes[0] / D;   // 50000
    const int E = in_sizes[1];       // 800000

    // Workspace layout (bytes):
    //   support : n*96 halves   (9.6 MB)
    //   head    : n ints        (200 KB)
    //   next    : E ints        (3.2 MB)
    //   cv      : E int2        (6.4 MB)
    //   bfrag   : 9216 ushort   (18 KB)  -- offset 19,400,000 (16B aligned)
    __half*         support = (__half*)d_ws;
    int*            head    = (int*)((char*)d_ws + (size_t)n * D * sizeof(__half));
    int*            next    = head + n;
    int2*           cv      = (int2*)(next + E);
    unsigned short* bfrag   = (unsigned short*)(cv + E);

    hipMemsetAsync(head, 0xFF, (size_t)n * sizeof(int), stream);  // head[r] = -1

    prep_bfrags<<<4, 256, 0, stream>>>(w, bfrag);
    build_lists<<<(E + 255) / 256, 256, 0, stream>>>(erow, ecol, eval_, head, next, cv, E);
    gemm_mfma<<<(n / 16 + 3) / 4, 256, 0, stream>>>(x, bfrag, support, n);
    accumulate_ll<<<(n + 15) / 16, 192, 0, stream>>>(head, next, cv, support, b, out, n);
}

// Round 6
// 182.251 us; speedup vs baseline: 6.0158x; 1.0085x over previous
//
#include <hip/hip_runtime.h>
#include <hip/hip_fp16.h>

#define D 96

typedef __attribute__((ext_vector_type(8))) short short8;
typedef __attribute__((ext_vector_type(4))) float f32x4;

__device__ inline unsigned short f32_to_bf16_rne(float f) {
    unsigned int u = __float_as_uint(f);
    unsigned int r = u + 0x7FFFu + ((u >> 16) & 1u);
    return (unsigned short)(r >> 16);
}

// -------- fused: [blocks 0..gbGemm) GEMM via MFMA] + [blocks gbGemm..) build lists --------
// GEMM role: stage W into LDS (stride 97), each wave builds 18 B-frags + does a 16-row tile.
// Build role: per-row linked lists via atomicExch + packed (col,val). Independent of GEMM.
__global__ __launch_bounds__(256) void fused_gemm_build(
        const float* __restrict__ x, const float* __restrict__ w,
        const int* __restrict__ erow, const int* __restrict__ ecol,
        const float* __restrict__ eval_,
        __half* __restrict__ support,
        int* __restrict__ head, int* __restrict__ next, int2* __restrict__ cv,
        int n, int E, int gbGemm) {
    __shared__ float Wl[96 * 97];
    const int tid = threadIdx.x;

    if (blockIdx.x >= gbGemm) {
        // ---- build role ----
        int e = (blockIdx.x - gbGemm) * 256 + tid;
        if (e < E) {
            next[e] = atomicExch(&head[erow[e]], e);
            cv[e] = make_int2(ecol[e], __float_as_int(eval_[e]));
        }
        return;
    }

    // ---- GEMM role ----
    // Stage W (96x96) into LDS with row stride 97 (pad kills quad-aligned bank conflicts).
    {
        const float4* w4 = (const float4*)w;
        #pragma unroll
        for (int it = 0; it < 9; it++) {
            int i4 = tid + it * 256;
            if (i4 < 2304) {
                int r = i4 / 24, c = i4 - (i4 / 24) * 24;
                float4 v = w4[i4];
                float* dst = &Wl[r * 97 + c * 4];
                dst[0] = v.x; dst[1] = v.y; dst[2] = v.z; dst[3] = v.w;
            }
        }
    }
    __syncthreads();

    const int lane = tid & 63;
    const int wave = tid >> 6;
    const int m0 = (blockIdx.x * 4 + wave) * 16;
    if (m0 >= n) return;

    const int quad = lane >> 4;
    const int col = lane & 15;

    // Build 18 B-frags from LDS: frag f=ct*3+kc, element j = W[kc*32+quad*8+j][ct*16+col].
    short8 bf[18];
    #pragma unroll
    for (int f = 0; f < 18; f++) {
        int ct = f / 3, kc = f - ct * 3;
        const float* base = &Wl[(kc * 32 + quad * 8) * 97 + ct * 16 + col];
        #pragma unroll
        for (int j = 0; j < 8; j++) bf[f][j] = (short)f32_to_bf16_rne(base[j * 97]);
    }

    f32x4 acc[6];
    #pragma unroll
    for (int ct = 0; ct < 6; ct++) acc[ct] = (f32x4){0.f, 0.f, 0.f, 0.f};

    const int row = m0 + col;
    const float4* xrow = (const float4*)(x + (size_t)row * D);

    #pragma unroll
    for (int kc = 0; kc < 3; kc++) {
        float4 f0 = xrow[kc * 8 + quad * 2 + 0];
        float4 f1 = xrow[kc * 8 + quad * 2 + 1];
        short8 a;
        a[0] = (short)f32_to_bf16_rne(f0.x);
        a[1] = (short)f32_to_bf16_rne(f0.y);
        a[2] = (short)f32_to_bf16_rne(f0.z);
        a[3] = (short)f32_to_bf16_rne(f0.w);
        a[4] = (short)f32_to_bf16_rne(f1.x);
        a[5] = (short)f32_to_bf16_rne(f1.y);
        a[6] = (short)f32_to_bf16_rne(f1.z);
        a[7] = (short)f32_to_bf16_rne(f1.w);
        #pragma unroll
        for (int ct = 0; ct < 6; ct++)
            acc[ct] = __builtin_amdgcn_mfma_f32_16x16x32_bf16(a, bf[ct * 3 + kc], acc[ct], 0, 0, 0);
    }

    // Epilogue: D[row=quad*4+j][col] per col-tile, emit fp16.
    const int rbase = m0 + quad * 4;
    #pragma unroll
    for (int ct = 0; ct < 6; ct++) {
        #pragma unroll
        for (int j = 0; j < 4; j++) {
            support[(size_t)(rbase + j) * D + ct * 16 + col] = __float2half(acc[ct][j]);
        }
    }
}

// -------- segment-sum via list traversal, fp16 support gathers --------
// 12 lanes per row (16B chunk each), 16 rows per 192-thread block.
// next/cv loaded non-temporally (single-use streams) so L2 capacity goes to support.
__global__ __launch_bounds__(192) void accumulate_ll(const int* __restrict__ head,
                                                     const int* __restrict__ next,
                                                     const int2* __restrict__ cv,
                                                     const __half* __restrict__ support,
                                                     const float* __restrict__ b,
                                                     float* __restrict__ out,
                                                     int N) {
    const int tid = threadIdx.x;
    const int rl = tid / 12;
    const int c = tid - rl * 12;
    const int r = blockIdx.x * 16 + rl;
    if (r >= N) return;

    float4 accA = ((const float4*)b)[c * 2];
    float4 accB = ((const float4*)b)[c * 2 + 1];

    const float4* sup16 = (const float4*)support;

    int e = head[r];
    while (e >= 0) {
        long long cvv = __builtin_nontemporal_load((const long long*)&cv[e]);
        int en = __builtin_nontemporal_load(&next[e]);   // chase load issued early
        int colI = (int)(cvv & 0xffffffffLL);
        float v = __int_as_float((int)(cvv >> 32));
        float4 raw = sup16[(size_t)colI * 12 + c];       // cached gather (the hot stream)
        const __half2* h = (const __half2*)&raw;
        float2 f0 = __half22float2(h[0]);
        float2 f1 = __half22float2(h[1]);
        float2 f2 = __half22float2(h[2]);
        float2 f3 = __half22float2(h[3]);
        accA.x += v * f0.x;  accA.y += v * f0.y;
        accA.z += v * f1.x;  accA.w += v * f1.y;
        accB.x += v * f2.x;  accB.y += v * f2.y;
        accB.z += v * f3.x;  accB.w += v * f3.y;
        e = en;
    }
    float* o = out + (size_t)r * D + c * 8;
    f32x4 sA = {accA.x, accA.y, accA.z, accA.w};
    f32x4 sB = {accB.x, accB.y, accB.z, accB.w};
    __builtin_nontemporal_store(sA, (f32x4*)o);
    __builtin_nontemporal_store(sB, (f32x4*)(o + 4));
}

extern "C" void kernel_launch(void* const* d_in, const int* in_sizes, int n_in,
                              void* d_out, int out_size, void* d_ws, size_t ws_size,
                              hipStream_t stream) {
    const float* x     = (const float*)d_in[0];
    const int*   erow  = (const int*)d_in[1];
    const int*   ecol  = (const int*)d_in[2];
    const float* eval_ = (const float*)d_in[3];
    const float* w     = (const float*)d_in[4];
    const float* b     = (const float*)d_in[5];
    float* out = (float*)d_out;

    const int n = in_sizes[0] / D;   // 50000
    const int E = in_sizes[1];       // 800000

    // Workspace layout (bytes):
    //   support : n*96 halves  (9.6 MB)
    //   head    : n ints       (200 KB)
    //   next    : E ints       (3.2 MB)
    //   cv      : E int2       (6.4 MB) -- offset 13,000,000, 8B aligned
    __half* support = (__half*)d_ws;
    int*    head    = (int*)((char*)d_ws + (size_t)n * D * sizeof(__half));
    int*    next    = head + n;
    int2*   cv      = (int2*)(next + E);

    hipMemsetAsync(head, 0xFF, (size_t)n * sizeof(int), stream);  // head[r] = -1

    const int gbGemm = (n + 63) / 64;          // 782
    const int gbBuild = (E + 255) / 256;       // 3125
    fused_gemm_build<<<gbGemm + gbBuild, 256, 0, stream>>>(
        x, w, erow, ecol, eval_, support, head, next, cv, n, E, gbGemm);
    accumulate_ll<<<(n + 15) / 16, 192, 0, stream>>>(head, next, cv, support, b, out, n);
}

// Round 7
// 175.178 us; speedup vs baseline: 6.2587x; 1.0404x over previous
//
#include <hip/hip_runtime.h>
#include <hip/hip_fp16.h>

#define D 96
#define CHSHIFT 13                    // source-node chunk = col >> 13 (8192 rows = 1.57 MB fp16)

typedef __attribute__((ext_vector_type(8))) short short8;
typedef __attribute__((ext_vector_type(4))) float f32x4;

__device__ inline unsigned short f32_to_bf16_rne(float f) {
    unsigned int u = __float_as_uint(f);
    unsigned int r = u + 0x7FFFu + ((u >> 16) & 1u);
    return (unsigned short)(r >> 16);
}

// -------- fused: [blocks 0..gbGemm) MFMA GEMM] + [blocks gbGemm..) chunked list build --------
__global__ __launch_bounds__(256) void fused_gemm_build(
        const float* __restrict__ x, const float* __restrict__ w,
        const int* __restrict__ erow, const int* __restrict__ ecol,
        const float* __restrict__ eval_,
        __half* __restrict__ support,
        int* __restrict__ head, int* __restrict__ next, int2* __restrict__ cv,
        int n, int E, int gbGemm) {
    __shared__ unsigned short Wl[96 * 98];   // bf16 W, stride-98 pad (18.8 KB -> 8 blocks/CU)
    const int tid = threadIdx.x;

    if (blockIdx.x >= gbGemm) {
        // ---- build role: per-(row, col-chunk) linked lists ----
        int e = (blockIdx.x - gbGemm) * 256 + tid;
        if (e < E) {
            int r = erow[e];
            int c = ecol[e];
            int ch = c >> CHSHIFT;
            next[e] = atomicExch(&head[ch * n + r], e);
            cv[e] = make_int2(c, __float_as_int(eval_[e]));
        }
        return;
    }

    // ---- GEMM role ----
    // Stage W (96x96 fp32 -> bf16) into LDS, row stride 98 ushorts.
    {
        const float4* w4 = (const float4*)w;
        #pragma unroll
        for (int it = 0; it < 9; it++) {
            int i4 = tid + it * 256;
            if (i4 < 2304) {
                int r = i4 / 24, c = i4 - (i4 / 24) * 24;
                float4 v = w4[i4];
                unsigned int p0 = (unsigned int)f32_to_bf16_rne(v.x) |
                                  ((unsigned int)f32_to_bf16_rne(v.y) << 16);
                unsigned int p1 = (unsigned int)f32_to_bf16_rne(v.z) |
                                  ((unsigned int)f32_to_bf16_rne(v.w) << 16);
                unsigned int* dst = (unsigned int*)&Wl[r * 98 + c * 4];
                dst[0] = p0; dst[1] = p1;
            }
        }
    }
    __syncthreads();

    const int lane = tid & 63;
    const int wave = tid >> 6;
    const int m0 = (blockIdx.x * 4 + wave) * 16;
    if (m0 >= n) return;

    const int quad = lane >> 4;
    const int col = lane & 15;

    // B-frags from LDS: frag f=ct*3+kc, element j = W[kc*32+quad*8+j][ct*16+col].
    short8 bf[18];
    #pragma unroll
    for (int f = 0; f < 18; f++) {
        int ct = f / 3, kc = f - ct * 3;
        const unsigned short* base = &Wl[(kc * 32 + quad * 8) * 98 + ct * 16 + col];
        #pragma unroll
        for (int j = 0; j < 8; j++) bf[f][j] = (short)base[j * 98];
    }

    f32x4 acc[6];
    #pragma unroll
    for (int ct = 0; ct < 6; ct++) acc[ct] = (f32x4){0.f, 0.f, 0.f, 0.f};

    const int row = m0 + col;
    const float4* xrow = (const float4*)(x + (size_t)row * D);

    #pragma unroll
    for (int kc = 0; kc < 3; kc++) {
        float4 f0 = xrow[kc * 8 + quad * 2 + 0];
        float4 f1 = xrow[kc * 8 + quad * 2 + 1];
        short8 a;
        a[0] = (short)f32_to_bf16_rne(f0.x);
        a[1] = (short)f32_to_bf16_rne(f0.y);
        a[2] = (short)f32_to_bf16_rne(f0.z);
        a[3] = (short)f32_to_bf16_rne(f0.w);
        a[4] = (short)f32_to_bf16_rne(f1.x);
        a[5] = (short)f32_to_bf16_rne(f1.y);
        a[6] = (short)f32_to_bf16_rne(f1.z);
        a[7] = (short)f32_to_bf16_rne(f1.w);
        #pragma unroll
        for (int ct = 0; ct < 6; ct++)
            acc[ct] = __builtin_amdgcn_mfma_f32_16x16x32_bf16(a, bf[ct * 3 + kc], acc[ct], 0, 0, 0);
    }

    // Epilogue: D[row=quad*4+j][col] per col-tile, emit fp16.
    const int rbase = m0 + quad * 4;
    #pragma unroll
    for (int ct = 0; ct < 6; ct++) {
        #pragma unroll
        for (int j = 0; j < 4; j++) {
            support[(size_t)(rbase + j) * D + ct * 16 + col] = __float2half(acc[ct][j]);
        }
    }
}

// -------- segment-sum: traverse the per-chunk chains in chunk order --------
// 12 lanes per row (16B chunk each), 16 rows per 192-thread block. All resident blocks
// walk source-chunk c before c+1, keeping ~1.6 MB of support hot in each XCD L2.
__global__ __launch_bounds__(192) void accumulate_ll(const int* __restrict__ head,
                                                     const int* __restrict__ next,
                                                     const int2* __restrict__ cv,
                                                     const __half* __restrict__ support,
                                                     const float* __restrict__ b,
                                                     float* __restrict__ out,
                                                     int N, int nch) {
    const int tid = threadIdx.x;
    const int rl = tid / 12;
    const int c = tid - rl * 12;
    const int r = blockIdx.x * 16 + rl;
    if (r >= N) return;

    float4 accA = ((const float4*)b)[c * 2];
    float4 accB = ((const float4*)b)[c * 2 + 1];

    const float4* sup16 = (const float4*)support;

    for (int ch = 0; ch < nch; ch++) {
        int e = head[ch * N + r];
        while (e >= 0) {
            int2 cvv = cv[e];
            int en = next[e];                         // chase load issued early
            float v = __int_as_float(cvv.y);
            float4 raw = sup16[(size_t)cvv.x * 12 + c];
            const __half2* h = (const __half2*)&raw;
            float2 f0 = __half22float2(h[0]);
            float2 f1 = __half22float2(h[1]);
            float2 f2 = __half22float2(h[2]);
            float2 f3 = __half22float2(h[3]);
            accA.x += v * f0.x;  accA.y += v * f0.y;
            accA.z += v * f1.x;  accA.w += v * f1.y;
            accB.x += v * f2.x;  accB.y += v * f2.y;
            accB.z += v * f3.x;  accB.w += v * f3.y;
            e = en;
        }
    }
    float* o = out + (size_t)r * D + c * 8;
    f32x4 sA = {accA.x, accA.y, accA.z, accA.w};
    f32x4 sB = {accB.x, accB.y, accB.z, accB.w};
    __builtin_nontemporal_store(sA, (f32x4*)o);       // out is write-once: keep it out of L2
    __builtin_nontemporal_store(sB, (f32x4*)(o + 4));
}

extern "C" void kernel_launch(void* const* d_in, const int* in_sizes, int n_in,
                              void* d_out, int out_size, void* d_ws, size_t ws_size,
                              hipStream_t stream) {
    const float* x     = (const float*)d_in[0];
    const int*   erow  = (const int*)d_in[1];
    const int*   ecol  = (const int*)d_in[2];
    const float* eval_ = (const float*)d_in[3];
    const float* w     = (const float*)d_in[4];
    const float* b     = (const float*)d_in[5];
    float* out = (float*)d_out;

    const int n = in_sizes[0] / D;          // 50000
    const int E = in_sizes[1];              // 800000
    const int nch = ((n - 1) >> CHSHIFT) + 1;  // 7 source-node chunks

    // Workspace layout (bytes):
    //   support : n*96 halves      (9.6 MB)
    //   head    : nch*n ints       (1.4 MB)
    //   next    : E ints           (3.2 MB)
    //   cv      : E int2           (6.4 MB)   total ~20.6 MB
    __half* support = (__half*)d_ws;
    int*    head    = (int*)((char*)d_ws + (size_t)n * D * sizeof(__half));
    int*    next    = head + (size_t)nch * n;
    int2*   cv      = (int2*)(next + E);

    hipMemsetAsync(head, 0xFF, (size_t)nch * n * sizeof(int), stream);  // all heads = -1

    const int gbGemm = (n + 63) / 64;          // 782
    const int gbBuild = (E + 255) / 256;       // 3125
    fused_gemm_build<<<gbGemm + gbBuild, 256, 0, stream>>>(
        x, w, erow, ecol, eval_, support, head, next, cv, n, E, gbGemm);
    accumulate_ll<<<(n + 15) / 16, 192, 0, stream>>>(head, next, cv, support, b, out, n, nch);
}

// Round 8
// 166.833 us; speedup vs baseline: 6.5718x; 1.0500x over previous
//
#include <hip/hip_runtime.h>
#include <hip/hip_fp16.h>

#define D 96
#define NCH 4   // independent chains per row (MLP)

typedef __attribute__((ext_vector_type(8))) short short8;
typedef __attribute__((ext_vector_type(4))) float f32x4;

__device__ inline unsigned short f32_to_bf16_rne(float f) {
    unsigned int u = __float_as_uint(f);
    unsigned int r = u + 0x7FFFu + ((u >> 16) & 1u);
    return (unsigned short)(r >> 16);
}

// -------- fused: [blocks 0..gbGemm) MFMA GEMM] + [blocks gbGemm..) 4-chain list build --------
__global__ __launch_bounds__(256) void fused_gemm_build(
        const float* __restrict__ x, const float* __restrict__ w,
        const int* __restrict__ erow, const int* __restrict__ ecol,
        const float* __restrict__ eval_,
        __half* __restrict__ support,
        int* __restrict__ head, int* __restrict__ next, int2* __restrict__ cv,
        int n, int E, int gbGemm) {
    __shared__ unsigned short Wl[96 * 98];   // bf16 W, stride-98 pad
    const int tid = threadIdx.x;

    if (blockIdx.x >= gbGemm) {
        // ---- build role: 4 independent chains per row, keyed by edge low bits ----
        int e = (blockIdx.x - gbGemm) * 256 + tid;
        if (e < E) {
            int r = erow[e];
            next[e] = atomicExch(&head[(r << 2) | (e & 3)], e);
            cv[e] = make_int2(ecol[e], __float_as_int(eval_[e]));
        }
        return;
    }

    // ---- GEMM role ----
    {
        const float4* w4 = (const float4*)w;
        #pragma unroll
        for (int it = 0; it < 9; it++) {
            int i4 = tid + it * 256;
            if (i4 < 2304) {
                int r = i4 / 24, c = i4 - (i4 / 24) * 24;
                float4 v = w4[i4];
                unsigned int p0 = (unsigned int)f32_to_bf16_rne(v.x) |
                                  ((unsigned int)f32_to_bf16_rne(v.y) << 16);
                unsigned int p1 = (unsigned int)f32_to_bf16_rne(v.z) |
                                  ((unsigned int)f32_to_bf16_rne(v.w) << 16);
                unsigned int* dst = (unsigned int*)&Wl[r * 98 + c * 4];
                dst[0] = p0; dst[1] = p1;
            }
        }
    }
    __syncthreads();

    const int lane = tid & 63;
    const int wave = tid >> 6;
    const int m0 = (blockIdx.x * 4 + wave) * 16;
    if (m0 >= n) return;

    const int quad = lane >> 4;
    const int col = lane & 15;

    short8 bf[18];
    #pragma unroll
    for (int f = 0; f < 18; f++) {
        int ct = f / 3, kc = f - ct * 3;
        const unsigned short* base = &Wl[(kc * 32 + quad * 8) * 98 + ct * 16 + col];
        #pragma unroll
        for (int j = 0; j < 8; j++) bf[f][j] = (short)base[j * 98];
    }

    f32x4 acc[6];
    #pragma unroll
    for (int ct = 0; ct < 6; ct++) acc[ct] = (f32x4){0.f, 0.f, 0.f, 0.f};

    const int row = m0 + col;
    const float4* xrow = (const float4*)(x + (size_t)row * D);

    #pragma unroll
    for (int kc = 0; kc < 3; kc++) {
        float4 f0 = xrow[kc * 8 + quad * 2 + 0];
        float4 f1 = xrow[kc * 8 + quad * 2 + 1];
        short8 a;
        a[0] = (short)f32_to_bf16_rne(f0.x);
        a[1] = (short)f32_to_bf16_rne(f0.y);
        a[2] = (short)f32_to_bf16_rne(f0.z);
        a[3] = (short)f32_to_bf16_rne(f0.w);
        a[4] = (short)f32_to_bf16_rne(f1.x);
        a[5] = (short)f32_to_bf16_rne(f1.y);
        a[6] = (short)f32_to_bf16_rne(f1.z);
        a[7] = (short)f32_to_bf16_rne(f1.w);
        #pragma unroll
        for (int ct = 0; ct < 6; ct++)
            acc[ct] = __builtin_amdgcn_mfma_f32_16x16x32_bf16(a, bf[ct * 3 + kc], acc[ct], 0, 0, 0);
    }

    const int rbase = m0 + quad * 4;
    #pragma unroll
    for (int ct = 0; ct < 6; ct++) {
        #pragma unroll
        for (int j = 0; j < 4; j++) {
            support[(size_t)(rbase + j) * D + ct * 16 + col] = __float2half(acc[ct][j]);
        }
    }
}

// -------- segment-sum: walk 4 chains per row concurrently (4x MLP) --------
// 12 lanes per row (16B chunk each), 16 rows per 192-thread block.
__global__ __launch_bounds__(192) void accumulate_ll(const int* __restrict__ head,
                                                     const int* __restrict__ next,
                                                     const int2* __restrict__ cv,
                                                     const __half* __restrict__ support,
                                                     const float* __restrict__ b,
                                                     float* __restrict__ out,
                                                     int N) {
    const int tid = threadIdx.x;
    const int rl = tid / 12;
    const int c = tid - rl * 12;
    const int r = blockIdx.x * 16 + rl;
    if (r >= N) return;

    float4 accA = ((const float4*)b)[c * 2];
    float4 accB = ((const float4*)b)[c * 2 + 1];

    const float4* sup16 = (const float4*)support;

    int e0 = head[(r << 2) | 0];
    int e1 = head[(r << 2) | 1];
    int e2 = head[(r << 2) | 2];
    int e3 = head[(r << 2) | 3];

    while (e0 >= 0 || e1 >= 0 || e2 >= 0 || e3 >= 0) {
        bool a0 = e0 >= 0, a1 = e1 >= 0, a2 = e2 >= 0, a3 = e3 >= 0;
        int i0 = a0 ? e0 : 0, i1 = a1 ? e1 : 0, i2 = a2 ? e2 : 0, i3 = a3 ? e3 : 0;

        // Issue all chase/cv loads first, then all gathers (max outstanding).
        int2 q0 = cv[i0]; int2 q1 = cv[i1]; int2 q2 = cv[i2]; int2 q3 = cv[i3];
        int n0 = next[i0]; int n1 = next[i1]; int n2 = next[i2]; int n3 = next[i3];

        float4 g0 = sup16[(size_t)q0.x * 12 + c];
        float4 g1 = sup16[(size_t)q1.x * 12 + c];
        float4 g2 = sup16[(size_t)q2.x * 12 + c];
        float4 g3 = sup16[(size_t)q3.x * 12 + c];

        float v0 = a0 ? __int_as_float(q0.y) : 0.f;
        float v1 = a1 ? __int_as_float(q1.y) : 0.f;
        float v2 = a2 ? __int_as_float(q2.y) : 0.f;
        float v3 = a3 ? __int_as_float(q3.y) : 0.f;

        const __half2* h;
        h = (const __half2*)&g0;
        { float2 f0 = __half22float2(h[0]), f1 = __half22float2(h[1]),
                 f2 = __half22float2(h[2]), f3 = __half22float2(h[3]);
          accA.x += v0 * f0.x; accA.y += v0 * f0.y; accA.z += v0 * f1.x; accA.w += v0 * f1.y;
          accB.x += v0 * f2.x; accB.y += v0 * f2.y; accB.z += v0 * f3.x; accB.w += v0 * f3.y; }
        h = (const __half2*)&g1;
        { float2 f0 = __half22float2(h[0]), f1 = __half22float2(h[1]),
                 f2 = __half22float2(h[2]), f3 = __half22float2(h[3]);
          accA.x += v1 * f0.x; accA.y += v1 * f0.y; accA.z += v1 * f1.x; accA.w += v1 * f1.y;
          accB.x += v1 * f2.x; accB.y += v1 * f2.y; accB.z += v1 * f3.x; accB.w += v1 * f3.y; }
        h = (const __half2*)&g2;
        { float2 f0 = __half22float2(h[0]), f1 = __half22float2(h[1]),
                 f2 = __half22float2(h[2]), f3 = __half22float2(h[3]);
          accA.x += v2 * f0.x; accA.y += v2 * f0.y; accA.z += v2 * f1.x; accA.w += v2 * f1.y;
          accB.x += v2 * f2.x; accB.y += v2 * f2.y; accB.z += v2 * f3.x; accB.w += v2 * f3.y; }
        h = (const __half2*)&g3;
        { float2 f0 = __half22float2(h[0]), f1 = __half22float2(h[1]),
                 f2 = __half22float2(h[2]), f3 = __half22float2(h[3]);
          accA.x += v3 * f0.x; accA.y += v3 * f0.y; accA.z += v3 * f1.x; accA.w += v3 * f1.y;
          accB.x += v3 * f2.x; accB.y += v3 * f2.y; accB.z += v3 * f3.x; accB.w += v3 * f3.y; }

        e0 = a0 ? n0 : -1;
        e1 = a1 ? n1 : -1;
        e2 = a2 ? n2 : -1;
        e3 = a3 ? n3 : -1;
    }

    float* o = out + (size_t)r * D + c * 8;
    f32x4 sA = {accA.x, accA.y, accA.z, accA.w};
    f32x4 sB = {accB.x, accB.y, accB.z, accB.w};
    __builtin_nontemporal_store(sA, (f32x4*)o);
    __builtin_nontemporal_store(sB, (f32x4*)(o + 4));
}

extern "C" void kernel_launch(void* const* d_in, const int* in_sizes, int n_in,
                              void* d_out, int out_size, void* d_ws, size_t ws_size,
                              hipStream_t stream) {
    const float* x     = (const float*)d_in[0];
    const int*   erow  = (const int*)d_in[1];
    const int*   ecol  = (const int*)d_in[2];
    const float* eval_ = (const float*)d_in[3];
    const float* w     = (const float*)d_in[4];
    const float* b     = (const float*)d_in[5];
    float* out = (float*)d_out;

    const int n = in_sizes[0] / D;   // 50000
    const int E = in_sizes[1];       // 800000

    // Workspace layout (bytes):
    //   support : n*96 halves   (9.6 MB)
    //   head    : 4*n ints      (800 KB)
    //   next    : E ints        (3.2 MB)
    //   cv      : E int2        (6.4 MB)
    __half* support = (__half*)d_ws;
    int*    head    = (int*)((char*)d_ws + (size_t)n * D * sizeof(__half));
    int*    next    = head + (size_t)NCH * n;
    int2*   cv      = (int2*)(next + E);

    hipMemsetAsync(head, 0xFF, (size_t)NCH * n * sizeof(int), stream);  // heads = -1

    const int gbGemm = (n + 63) / 64;          // 782
    const int gbBuild = (E + 255) / 256;       // 3125
    fused_gemm_build<<<gbGemm + gbBuild, 256, 0, stream>>>(
        x, w, erow, ecol, eval_, support, head, next, cv, n, E, gbGemm);
    accumulate_ll<<<(n + 15) / 16, 192, 0, stream>>>(head, next, cv, support, b, out, n);
}